// Round 1
// baseline (3075.387 us; speedup 1.0000x reference)
//
#include <hip/hip_runtime.h>

// ---------------------------------------------------------------------------
// Graph U-Net (GCN + SAGPool encoder / unpool decoder) on MI355X, fp32.
// Key choices:
//  - dense A0 (4096^2 f32) built from edges; A1a/A2a dense f32 + bitset forms
//  - augment (A@A>0) done as bitset row-union (sparse, ~nnz^2 work)
//  - A1/A2/A3 dense never materialized (A3 is unused by the reference)
//  - GCN normalization folded into GEMM epilogue (kscale/rowscale/bias/relu)
//  - top-k via exact O(N^2) rank with scores in LDS (matches lax.top_k order)
//  - final layer reassociated: (An@up)@W instead of An@(up@W)  (8.4G->1.2G MAC)
// ---------------------------------------------------------------------------

constexpr int NN  = 4096;
constexpr int EE  = 65536;
constexpr int FIN = 500;
constexpr int HH  = 64;
constexpr int KK1 = 3277, KK2 = 2622, KK3 = 2098;
constexpr int W1  = (KK1 + 31) / 32;   // 103 words per bit-row
constexpr int W2  = (KK2 + 31) / 32;   // 82

// -------------------------------- utility ----------------------------------

__global__ void fill4_kernel(float4* p, long n4) {
  long i = (long)blockIdx.x * blockDim.x + threadIdx.x;
  long stride = (long)gridDim.x * blockDim.x;
  float4 z = make_float4(0.f, 0.f, 0.f, 0.f);
  for (; i < n4; i += stride) p[i] = z;
}

__global__ void scatter_edges_kernel(float* A, const int* __restrict__ ei) {
  int e = blockIdx.x * 256 + threadIdx.x;
  if (e < EE) {
    int src = ei[e];        // edge_index[0][e]
    int dst = ei[EE + e];   // edge_index[1][e]
    A[(size_t)dst * NN + src] = 1.0f;   // A[dst, src] = 1
  }
  if (e < NN) A[(size_t)e * NN + e] = 1.0f;  // self loops
}

// dis[i] = rsqrt(rowsum) (rowsum >= 1 always due to self loop)
__global__ void rowsum_rsqrt_kernel(const float* __restrict__ A, float* dis,
                                    int ncols, int ld) {
  __shared__ float red[256];
  int row = blockIdx.x;
  const float* a = A + (size_t)row * ld;
  float s = 0.f;
  for (int j = threadIdx.x; j < ncols; j += 256) s += a[j];
  red[threadIdx.x] = s;
  __syncthreads();
  for (int off = 128; off > 0; off >>= 1) {
    if (threadIdx.x < off) red[threadIdx.x] += red[threadIdx.x + off];
    __syncthreads();
  }
  if (threadIdx.x == 0) {
    float d = red[0];
    dis[row] = d > 0.f ? rsqrtf(d) : 0.f;
  }
}

// s[row] = sum_j A[row][j]*t[j] + brel + r[row]
__global__ void matvec_score_kernel(const float* __restrict__ A, int ld, int ncols,
                                    const float* __restrict__ t,
                                    const float* __restrict__ r,
                                    const float* __restrict__ brel, float* s) {
  __shared__ float red[256];
  int row = blockIdx.x;
  const float* a = A + (size_t)row * ld;
  float acc = 0.f;
  for (int j = threadIdx.x; j < ncols; j += 256) acc += a[j] * t[j];
  red[threadIdx.x] = acc;
  __syncthreads();
  for (int off = 128; off > 0; off >>= 1) {
    if (threadIdx.x < off) red[threadIdx.x] += red[threadIdx.x + off];
    __syncthreads();
  }
  if (threadIdx.x == 0) s[row] = red[0] + brel[0] + r[row];
}

// out[r] = sum_f X[r][f]*w[f]   (X row stride 64; 4 rows per 256-thread block)
__global__ void rowdot64_kernel(const float* __restrict__ X,
                                const float* __restrict__ w, float* out, int M) {
  int lane = threadIdx.x & 63;
  int row = blockIdx.x * 4 + (threadIdx.x >> 6);
  if (row >= M) return;
  float v = X[(size_t)row * 64 + lane] * w[lane];
  for (int off = 32; off > 0; off >>= 1) v += __shfl_down(v, off, 64);
  if (lane == 0) out[row] = v;
}

// exact jax.lax.top_k: rank = #{s_j > s_i} + #{j<i : s_j == s_i}
__global__ void topk_kernel(const float* __restrict__ s, int n, int k,
                            int* perm, float* vals) {
  __shared__ float sh[4096];
  for (int j = threadIdx.x; j < n; j += 256) sh[j] = s[j];
  __syncthreads();
  int i = blockIdx.x * 256 + threadIdx.x;
  if (i >= n) return;
  float si = sh[i];
  int rank = 0;
  for (int j = 0; j < n; j++) {
    float sj = sh[j];
    if (sj > si || (sj == si && j < i)) rank++;
  }
  if (rank < k) { perm[rank] = i; vals[rank] = si; }
}

// out[r] = X[perm[r]] * tanh(vals[r])
__global__ void gather_gate_kernel(const float* __restrict__ X,
                                   const int* __restrict__ perm,
                                   const float* __restrict__ vals,
                                   float* out, int k) {
  int r = blockIdx.x * 4 + (threadIdx.x >> 6);
  int f = threadIdx.x & 63;
  if (r < k)
    out[(size_t)r * 64 + f] = X[(size_t)perm[r] * 64 + f] * tanhf(vals[r]);
}

// bits[r][*] = (dense[perm[r]][perm[c]] != 0) for c in [0,K)
__global__ void build_bits_kernel(const float* __restrict__ dense, int ld,
                                  const int* __restrict__ perm, int K, int Wd,
                                  unsigned* bits) {
  int r = blockIdx.x;
  const float* rowp = dense + (size_t)perm[r] * ld;
  unsigned* ob = bits + (size_t)r * Wd;
  for (int c0 = 0; c0 < Wd * 32; c0 += 256) {
    int c = c0 + threadIdx.x;
    bool pred = false;
    if (c < K) pred = (rowp[perm[c]] != 0.f);
    unsigned long long m = __ballot(pred);
    if ((threadIdx.x & 63) == 0) {
      int wb = (c0 >> 5) + ((threadIdx.x >> 6) << 1);
      if (wb < Wd)     ob[wb]     = (unsigned)m;
      if (wb + 1 < Wd) ob[wb + 1] = (unsigned)(m >> 32);
    }
  }
}

// out_row[i] = OR of in_row[j] for every set bit j of in_row[i]  (== A^2 > 0)
__global__ void augment_or_kernel(const unsigned* __restrict__ in,
                                  unsigned* __restrict__ out, int Wd) {
  __shared__ unsigned roww[128];
  __shared__ int nbr[3328];          // max degree <= K1 = 3277
  __shared__ int cnt;
  int i = blockIdx.x;
  if (threadIdx.x == 0) cnt = 0;
  const unsigned* rin = in + (size_t)i * Wd;
  for (int w = threadIdx.x; w < Wd; w += 128) roww[w] = rin[w];
  __syncthreads();
  for (int w = threadIdx.x; w < Wd; w += 128) {
    unsigned m = roww[w];
    while (m) {
      int b = __ffs(m) - 1;
      m &= m - 1;
      nbr[atomicAdd(&cnt, 1)] = w * 32 + b;
    }
  }
  __syncthreads();
  int nc = cnt;
  for (int w = threadIdx.x; w < Wd; w += 128) {
    unsigned acc = 0;
    for (int q = 0; q < nc; q++) acc |= in[(size_t)nbr[q] * Wd + w];
    out[(size_t)i * Wd + w] = acc;
  }
}

__global__ void expand_bits_kernel(const unsigned* __restrict__ bits,
                                   float* dense, int K, int Wd) {
  int r = blockIdx.x;
  const unsigned* bw = bits + (size_t)r * Wd;
  float* dr = dense + (size_t)r * K;
  for (int c = threadIdx.x; c < K; c += 256)
    dr[c] = ((bw[c >> 5] >> (c & 31)) & 1u) ? 1.f : 0.f;
}

__global__ void scatter_rows_kernel(const float* __restrict__ z,
                                    const int* __restrict__ perm,
                                    float* up, int k) {
  int r = blockIdx.x * 4 + (threadIdx.x >> 6);
  int f = threadIdx.x & 63;
  if (r < k) up[(size_t)perm[r] * 64 + f] = z[(size_t)r * 64 + f];
}

// C[M x 64] = rowscale .* (A[M x K] @ (kscale .* B[K x 64])) + bias, opt relu
// block: 256 threads = 16 rows x 64 cols, K staged in 64-chunks through LDS.
__global__ void gemm64_kernel(const float* __restrict__ A, int lda,
                              const float* __restrict__ B,
                              const float* __restrict__ kscale,
                              const float* __restrict__ rowscale,
                              const float* __restrict__ bias,
                              float* __restrict__ C, int M, int K, int relu) {
  __shared__ float As[16][64];
  __shared__ float Bs[64][65];
  int f = threadIdx.x & 63;
  int rq = threadIdx.x >> 6;      // 0..3
  int row0 = blockIdx.x * 16;
  float acc0 = 0.f, acc1 = 0.f, acc2 = 0.f, acc3 = 0.f;
  for (int k0 = 0; k0 < K; k0 += 64) {
    for (int l = threadIdx.x; l < 16 * 64; l += 256) {
      int rr = l >> 6, kk = l & 63;
      int gr = row0 + rr, gk = k0 + kk;
      As[rr][kk] = (gr < M && gk < K) ? A[(size_t)gr * lda + gk] : 0.f;
    }
    for (int l = threadIdx.x; l < 64 * 64; l += 256) {
      int kk = l >> 6, ff = l & 63;
      int gk = k0 + kk;
      float v = 0.f;
      if (gk < K) {
        v = B[(size_t)gk * 64 + ff];
        if (kscale) v *= kscale[gk];
      }
      Bs[kk][ff] = v;
    }
    __syncthreads();
#pragma unroll 16
    for (int kk = 0; kk < 64; kk++) {
      float bv = Bs[kk][f];
      acc0 += As[rq][kk] * bv;
      acc1 += As[rq + 4][kk] * bv;
      acc2 += As[rq + 8][kk] * bv;
      acc3 += As[rq + 12][kk] * bv;
    }
    __syncthreads();
  }
  float accs[4] = {acc0, acc1, acc2, acc3};
  for (int i = 0; i < 4; i++) {
    int gr = row0 + rq + 4 * i;
    if (gr < M) {
      float v = accs[i];
      if (rowscale) v *= rowscale[gr];
      if (bias) v += bias[f];
      if (relu) v = fmaxf(v, 0.f);
      C[(size_t)gr * 64 + f] = v;
    }
  }
}

// out[M x 500] = Y[M x 64] @ B[64 x 500] + bias   (one row per block)
__global__ void gemm_wide_kernel(const float* __restrict__ Y,
                                 const float* __restrict__ B,
                                 const float* __restrict__ bias,
                                 float* __restrict__ C, int M) {
  __shared__ float ys[64];
  int r = blockIdx.x;
  if (threadIdx.x < 64) ys[threadIdx.x] = Y[(size_t)r * 64 + threadIdx.x];
  __syncthreads();
  int c = threadIdx.x;
  if (c < FIN) {
    float acc = bias[c];
#pragma unroll 16
    for (int k = 0; k < 64; k++) acc += ys[k] * B[k * FIN + c];
    C[(size_t)r * FIN + c] = acc;
  }
}

// ---------------------------------------------------------------------------

extern "C" void kernel_launch(void* const* d_in, const int* in_sizes, int n_in,
                              void* d_out, int out_size, void* d_ws, size_t ws_size,
                              hipStream_t stream) {
  const float* x      = (const float*)d_in[0];
  const float* w1     = (const float*)d_in[1];
  const float* b1     = (const float*)d_in[2];
  const float* w2     = (const float*)d_in[3];
  const float* b2     = (const float*)d_in[4];
  const float* w3     = (const float*)d_in[5];
  const float* b3     = (const float*)d_in[6];
  const float* p1wrel = (const float*)d_in[7];
  const float* p1brel = (const float*)d_in[8];
  const float* p1wroot= (const float*)d_in[9];
  const float* p2wrel = (const float*)d_in[10];
  const float* p2brel = (const float*)d_in[11];
  const float* p2wroot= (const float*)d_in[12];
  const float* p3wrel = (const float*)d_in[13];
  const float* p3brel = (const float*)d_in[14];
  const float* p3wroot= (const float*)d_in[15];
  const float* u0w    = (const float*)d_in[16];
  const float* u0b    = (const float*)d_in[17];
  const float* u1w    = (const float*)d_in[18];
  const float* u1b    = (const float*)d_in[19];
  const float* u2w    = (const float*)d_in[20];
  const float* u2b    = (const float*)d_in[21];
  const int*   ei     = (const int*)d_in[22];
  float* out = (float*)d_out;

  char* wp = (char*)d_ws;
  auto alloc = [&](size_t bytes) -> void* {
    void* p = (void*)wp;
    wp += (bytes + 255) & ~(size_t)255;
    return p;
  };
  float*    A0   = (float*)   alloc((size_t)NN  * NN  * 4);
  float*    A1a  = (float*)   alloc((size_t)KK1 * KK1 * 4);
  float*    A2a  = (float*)   alloc((size_t)KK2 * KK2 * 4);
  unsigned* A1b  = (unsigned*)alloc((size_t)KK1 * W1 * 4);
  unsigned* A1ab = (unsigned*)alloc((size_t)KK1 * W1 * 4);
  unsigned* A2b  = (unsigned*)alloc((size_t)KK2 * W2 * 4);
  unsigned* A2ab = (unsigned*)alloc((size_t)KK2 * W2 * 4);
  float*    dis0 = (float*)   alloc((size_t)NN * 4);
  float*    dis1 = (float*)   alloc((size_t)KK1 * 4);
  float*    dis2 = (float*)   alloc((size_t)KK2 * 4);
  float*    xw   = (float*)   alloc((size_t)NN  * HH * 4);
  float*    x1   = (float*)   alloc((size_t)NN  * HH * 4);
  float*    x1p  = (float*)   alloc((size_t)KK1 * HH * 4);
  float*    x2   = (float*)   alloc((size_t)KK1 * HH * 4);
  float*    x2p  = (float*)   alloc((size_t)KK2 * HH * 4);
  float*    x3   = (float*)   alloc((size_t)KK2 * HH * 4);
  float*    x3p  = (float*)   alloc((size_t)KK3 * HH * 4);
  float*    zd2  = (float*)   alloc((size_t)KK2 * HH * 4);
  float*    zd1  = (float*)   alloc((size_t)KK1 * HH * 4);
  float*    up   = (float*)   alloc((size_t)NN  * HH * 4);
  float*    y0   = (float*)   alloc((size_t)NN  * HH * 4);
  float*    tvec = (float*)   alloc((size_t)NN * 4);
  float*    rvec = (float*)   alloc((size_t)NN * 4);
  float*    svec = (float*)   alloc((size_t)NN * 4);
  float*    vals = (float*)   alloc((size_t)NN * 4);
  int*      perm1= (int*)     alloc((size_t)KK1 * 4);
  int*      perm2= (int*)     alloc((size_t)KK2 * 4);
  int*      perm3= (int*)     alloc((size_t)KK3 * 4);

  // ---- A0 (dense, with self loops) + normalization ----
  fill4_kernel<<<2048, 256, 0, stream>>>((float4*)A0, (long)NN * NN / 4);
  scatter_edges_kernel<<<EE / 256, 256, 0, stream>>>(A0, ei);
  rowsum_rsqrt_kernel<<<NN, 256, 0, stream>>>(A0, dis0, NN, NN);

  // ---- level 1: GCN -> score -> pool -> augment ----
  gemm64_kernel<<<(NN + 15) / 16, 256, 0, stream>>>(x, FIN, w1, nullptr, nullptr, nullptr, xw, NN, FIN, 0);
  gemm64_kernel<<<(NN + 15) / 16, 256, 0, stream>>>(A0, NN, xw, dis0, dis0, b1, x1, NN, NN, 0);
  rowdot64_kernel<<<(NN + 3) / 4, 256, 0, stream>>>(x1, p1wrel, tvec, NN);
  rowdot64_kernel<<<(NN + 3) / 4, 256, 0, stream>>>(x1, p1wroot, rvec, NN);
  matvec_score_kernel<<<NN, 256, 0, stream>>>(A0, NN, NN, tvec, rvec, p1brel, svec);
  topk_kernel<<<(NN + 255) / 256, 256, 0, stream>>>(svec, NN, KK1, perm1, vals);
  gather_gate_kernel<<<(KK1 + 3) / 4, 256, 0, stream>>>(x1, perm1, vals, x1p, KK1);
  build_bits_kernel<<<KK1, 256, 0, stream>>>(A0, NN, perm1, KK1, W1, A1b);
  augment_or_kernel<<<KK1, 128, 0, stream>>>(A1b, A1ab, W1);
  expand_bits_kernel<<<KK1, 256, 0, stream>>>(A1ab, A1a, KK1, W1);
  rowsum_rsqrt_kernel<<<KK1, 256, 0, stream>>>(A1a, dis1, KK1, KK1);

  // ---- level 2 ----
  gemm64_kernel<<<(KK1 + 15) / 16, 256, 0, stream>>>(x1p, HH, w2, nullptr, nullptr, nullptr, xw, KK1, HH, 0);
  gemm64_kernel<<<(KK1 + 15) / 16, 256, 0, stream>>>(A1a, KK1, xw, dis1, dis1, b2, x2, KK1, KK1, 0);
  rowdot64_kernel<<<(KK1 + 3) / 4, 256, 0, stream>>>(x2, p2wrel, tvec, KK1);
  rowdot64_kernel<<<(KK1 + 3) / 4, 256, 0, stream>>>(x2, p2wroot, rvec, KK1);
  matvec_score_kernel<<<KK1, 256, 0, stream>>>(A1a, KK1, KK1, tvec, rvec, p2brel, svec);
  topk_kernel<<<(KK1 + 255) / 256, 256, 0, stream>>>(svec, KK1, KK2, perm2, vals);
  gather_gate_kernel<<<(KK2 + 3) / 4, 256, 0, stream>>>(x2, perm2, vals, x2p, KK2);
  build_bits_kernel<<<KK2, 256, 0, stream>>>(A1a, KK1, perm2, KK2, W2, A2b);
  augment_or_kernel<<<KK2, 128, 0, stream>>>(A2b, A2ab, W2);
  expand_bits_kernel<<<KK2, 256, 0, stream>>>(A2ab, A2a, KK2, W2);
  rowsum_rsqrt_kernel<<<KK2, 256, 0, stream>>>(A2a, dis2, KK2, KK2);

  // ---- level 3 (A3 never needed) ----
  gemm64_kernel<<<(KK2 + 15) / 16, 256, 0, stream>>>(x2p, HH, w3, nullptr, nullptr, nullptr, xw, KK2, HH, 0);
  gemm64_kernel<<<(KK2 + 15) / 16, 256, 0, stream>>>(A2a, KK2, xw, dis2, dis2, b3, x3, KK2, KK2, 0);
  rowdot64_kernel<<<(KK2 + 3) / 4, 256, 0, stream>>>(x3, p3wrel, tvec, KK2);
  rowdot64_kernel<<<(KK2 + 3) / 4, 256, 0, stream>>>(x3, p3wroot, rvec, KK2);
  matvec_score_kernel<<<KK2, 256, 0, stream>>>(A2a, KK2, KK2, tvec, rvec, p3brel, svec);
  topk_kernel<<<(KK2 + 255) / 256, 256, 0, stream>>>(svec, KK2, KK3, perm3, vals);
  gather_gate_kernel<<<(KK3 + 3) / 4, 256, 0, stream>>>(x3, perm3, vals, x3p, KK3);

  // ---- decoder: unpool -> GCN(+relu) x2, final GCN reassociated ----
  fill4_kernel<<<256, 256, 0, stream>>>((float4*)up, (long)KK2 * HH / 4);
  scatter_rows_kernel<<<(KK3 + 3) / 4, 256, 0, stream>>>(x3p, perm3, up, KK3);
  gemm64_kernel<<<(KK2 + 15) / 16, 256, 0, stream>>>(up, HH, u0w, nullptr, nullptr, nullptr, xw, KK2, HH, 0);
  gemm64_kernel<<<(KK2 + 15) / 16, 256, 0, stream>>>(A2a, KK2, xw, dis2, dis2, u0b, zd2, KK2, KK2, 1);

  fill4_kernel<<<256, 256, 0, stream>>>((float4*)up, (long)KK1 * HH / 4);
  scatter_rows_kernel<<<(KK2 + 3) / 4, 256, 0, stream>>>(zd2, perm2, up, KK2);
  gemm64_kernel<<<(KK1 + 15) / 16, 256, 0, stream>>>(up, HH, u1w, nullptr, nullptr, nullptr, xw, KK1, HH, 0);
  gemm64_kernel<<<(KK1 + 15) / 16, 256, 0, stream>>>(A1a, KK1, xw, dis1, dis1, u1b, zd1, KK1, KK1, 1);

  fill4_kernel<<<256, 256, 0, stream>>>((float4*)up, (long)NN * HH / 4);
  scatter_rows_kernel<<<(KK1 + 3) / 4, 256, 0, stream>>>(zd1, perm1, up, KK1);
  // (An @ up) @ u2w + u2b   == An @ (up @ u2w) + u2b  (reassociated)
  gemm64_kernel<<<(NN + 15) / 16, 256, 0, stream>>>(A0, NN, up, dis0, dis0, nullptr, y0, NN, NN, 0);
  gemm_wide_kernel<<<NN, 512, 0, stream>>>(y0, u2w, u2b, out, NN);
}

// Round 2
// 641.418 us; speedup vs baseline: 4.7947x; 4.7947x over previous
//
#include <hip/hip_runtime.h>

// ---------------------------------------------------------------------------
// Graph U-Net (GCN + SAGPool encoder / unpool decoder) on MI355X, fp32.
// Round 2: all adjacencies as BITSETS. A@X via bitset SpMM (deg~17 / ~185);
// A2a (99.98% dense) via complement: colsum(B) - holes@B. Dense A never
// materialized. Feature GEMMs reshaped for occupancy (4 rows/block, grid ~1k).
// Top-k rank count split 2D with int atomics (deterministic).
// ---------------------------------------------------------------------------

constexpr int NN  = 4096;
constexpr int EE  = 65536;
constexpr int FIN = 500;
constexpr int KK1 = 3277, KK2 = 2622, KK3 = 2098;
constexpr int W0  = 128;               // words per A0 bit-row
constexpr int W1  = (KK1 + 31) / 32;   // 103
constexpr int W2  = (KK2 + 31) / 32;   // 82

// -------------------------------- utility ----------------------------------

__global__ void fill4_kernel(float4* p, long n4) {
  long i = (long)blockIdx.x * blockDim.x + threadIdx.x;
  long stride = (long)gridDim.x * blockDim.x;
  float4 z = make_float4(0.f, 0.f, 0.f, 0.f);
  for (; i < n4; i += stride) p[i] = z;
}

__global__ void scatter_bits_kernel(unsigned* Ab, const int* __restrict__ ei) {
  int e = blockIdx.x * 256 + threadIdx.x;
  if (e < EE) {
    int src = ei[e], dst = ei[EE + e];
    atomicOr(&Ab[(size_t)dst * W0 + (src >> 5)], 1u << (src & 31));
  }
  if (e < NN) atomicOr(&Ab[(size_t)e * W0 + (e >> 5)], 1u << (e & 31));
}

// dis[row] = rsqrt(popcount(bit row))
__global__ void popcnt_dis_kernel(const unsigned* __restrict__ bits, int Wd,
                                  float* dis, int M) {
  int lane = threadIdx.x & 63;
  int row = blockIdx.x * 4 + (threadIdx.x >> 6);
  if (row >= M) return;
  const unsigned* rb = bits + (size_t)row * Wd;
  int c = 0;
  for (int w = lane; w < Wd; w += 64) c += __popc(rb[w]);
  for (int off = 32; off; off >>= 1) c += __shfl_down(c, off, 64);
  if (!lane) dis[row] = c > 0 ? rsqrtf((float)c) : 0.f;
}

// C[M x 64]: add mode (base==null): C = rs .* (bits @ B) + bias
//            sub mode: C = rs .* (base - bits @ B) + bias   (complement trick)
__global__ void spmm_bits_kernel(const unsigned* __restrict__ bits, int Wd,
                                 const float* __restrict__ B,
                                 const float* __restrict__ base,
                                 const float* __restrict__ rowscale,
                                 const float* __restrict__ bias,
                                 float* __restrict__ C, int M, int relu) {
  int lane = threadIdx.x & 63;
  int row = blockIdx.x * 4 + (threadIdx.x >> 6);
  if (row >= M) return;
  const unsigned* rb = bits + (size_t)row * Wd;
  float acc = 0.f;
  for (int w = 0; w < Wd; w++) {
    unsigned m = rb[w];
    while (m) {
      int b = __ffs(m) - 1;
      m &= m - 1;
      acc += B[(size_t)((w << 5) + b) * 64 + lane];
    }
  }
  if (base) acc = base[lane] - acc;
  float v = acc * rowscale[row];
  if (bias) v += bias[lane];
  if (relu) v = fmaxf(v, 0.f);
  C[(size_t)row * 64 + lane] = v;
}

// s[row] = (total? total-sum : sum){t[j] : j in bits(row)} + brel + rv[row]
__global__ void matvec_bits_kernel(const unsigned* __restrict__ bits, int Wd,
                                   const float* __restrict__ t,
                                   const float* __restrict__ rv,
                                   const float* __restrict__ brel,
                                   const float* __restrict__ total,
                                   float* __restrict__ s, int M) {
  int lane = threadIdx.x & 63;
  int row = blockIdx.x * 4 + (threadIdx.x >> 6);
  if (row >= M) return;
  const unsigned* rb = bits + (size_t)row * Wd;
  float acc = 0.f;
  for (int w = lane; w < Wd; w += 64) {
    unsigned m = rb[w];
    while (m) {
      int b = __ffs(m) - 1;
      m &= m - 1;
      acc += t[(w << 5) + b];
    }
  }
  for (int off = 32; off; off >>= 1) acc += __shfl_down(acc, off, 64);
  if (!lane) {
    float r0 = total ? total[0] - acc : acc;
    s[row] = r0 + brel[0] + rv[row];
  }
}

// two dots per row: ta[r]=X[r].wa, tb[r]=X[r].wb
__global__ void rowdot2_kernel(const float* __restrict__ X,
                               const float* __restrict__ wa,
                               const float* __restrict__ wb,
                               float* ta, float* tb, int M) {
  int lane = threadIdx.x & 63;
  int row = blockIdx.x * 4 + (threadIdx.x >> 6);
  if (row >= M) return;
  float xv = X[(size_t)row * 64 + lane];
  float v1 = xv * wa[lane], v2 = xv * wb[lane];
  for (int off = 32; off; off >>= 1) {
    v1 += __shfl_down(v1, off, 64);
    v2 += __shfl_down(v2, off, 64);
  }
  if (!lane) { ta[row] = v1; tb[row] = v2; }
}

__global__ void vec_total_kernel(const float* __restrict__ t, int n, float* tot) {
  __shared__ float red[256];
  float a = 0.f;
  for (int i = threadIdx.x; i < n; i += 256) a += t[i];
  red[threadIdx.x] = a;
  __syncthreads();
  for (int o = 128; o; o >>= 1) {
    if (threadIdx.x < o) red[threadIdx.x] += red[threadIdx.x + o];
    __syncthreads();
  }
  if (!threadIdx.x) tot[0] = red[0];
}

// ---- top-k (exact lax.top_k order), 2D-split rank count ----
__global__ void topk_count_kernel(const float* __restrict__ s, int n, int* rank) {
  __shared__ float sh[512];
  int j0 = blockIdx.y * 512;
  for (int j = threadIdx.x; j < 512; j += 256) {
    int gj = j0 + j;
    sh[j] = gj < n ? s[gj] : 0.f;
  }
  __syncthreads();
  int i = blockIdx.x * 256 + threadIdx.x;
  if (i >= n) return;
  float si = s[i];
  int jmax = min(512, n - j0);
  int cnt = 0;
  for (int j = 0; j < jmax; j++) {
    float sj = sh[j];
    int gj = j0 + j;
    cnt += (sj > si || (sj == si && gj < i)) ? 1 : 0;
  }
  if (cnt) atomicAdd(&rank[i], cnt);
}

__global__ void topk_place_kernel(const float* __restrict__ s,
                                  const int* __restrict__ rank, int n, int k,
                                  int* perm, float* vals) {
  int i = blockIdx.x * 256 + threadIdx.x;
  if (i >= n) return;
  int rk = rank[i];
  if (rk < k) { perm[rk] = i; vals[rk] = s[i]; }
}

// out[r] = X[perm[r]] * tanh(vals[r]) * (rscale ? rscale[r] : 1)
__global__ void gather_gate_kernel(const float* __restrict__ X,
                                   const int* __restrict__ perm,
                                   const float* __restrict__ vals,
                                   const float* __restrict__ rscale,
                                   float* out, int k) {
  int r = blockIdx.x * 4 + (threadIdx.x >> 6);
  int f = threadIdx.x & 63;
  if (r < k) {
    float g = tanhf(vals[r]);
    if (rscale) g *= rscale[r];
    out[(size_t)r * 64 + f] = X[(size_t)perm[r] * 64 + f] * g;
  }
}

// up[perm[r]] = z[r] * scale[perm[r]]
__global__ void scatter_rows_kernel(const float* __restrict__ z,
                                    const int* __restrict__ perm,
                                    const float* __restrict__ scale,
                                    float* up, int k) {
  int r = blockIdx.x * 4 + (threadIdx.x >> 6);
  int f = threadIdx.x & 63;
  if (r < k) {
    int p = perm[r];
    up[(size_t)p * 64 + f] = z[(size_t)r * 64 + f] * scale[p];
  }
}

// out[r] bits = { Ab[perm[r]] bit perm[c] : c in [0,K) }
__global__ void subgraph_bits_kernel(const unsigned* __restrict__ Ab, int WdIn,
                                     const int* __restrict__ perm, int K, int WdOut,
                                     unsigned* __restrict__ out) {
  __shared__ unsigned rowb[128];
  int r = blockIdx.x;
  const unsigned* src = Ab + (size_t)perm[r] * WdIn;
  for (int w = threadIdx.x; w < WdIn; w += 256) rowb[w] = src[w];
  __syncthreads();
  unsigned* ob = out + (size_t)r * WdOut;
  for (int c0 = 0; c0 < WdOut * 32; c0 += 256) {
    int c = c0 + threadIdx.x;
    bool pred = false;
    if (c < K) {
      int pc = perm[c];
      pred = (rowb[pc >> 5] >> (pc & 31)) & 1u;
    }
    unsigned long long m = __ballot(pred);
    if ((threadIdx.x & 63) == 0) {
      int wb = (c0 >> 5) + ((threadIdx.x >> 6) << 1);
      if (wb < WdOut)     ob[wb]     = (unsigned)m;
      if (wb + 1 < WdOut) ob[wb + 1] = (unsigned)(m >> 32);
    }
  }
}

// out_row[i] = OR of in_row[j] over set bits j of in_row[i]  (== A^2 > 0)
__global__ void augment_or_kernel(const unsigned* __restrict__ in,
                                  unsigned* __restrict__ out, int Wd) {
  __shared__ unsigned roww[128];
  __shared__ int nbr[3328];
  __shared__ int cnt;
  int i = blockIdx.x;
  if (threadIdx.x == 0) cnt = 0;
  const unsigned* rin = in + (size_t)i * Wd;
  for (int w = threadIdx.x; w < Wd; w += 128) roww[w] = rin[w];
  __syncthreads();
  for (int w = threadIdx.x; w < Wd; w += 128) {
    unsigned m = roww[w];
    while (m) {
      int b = __ffs(m) - 1;
      m &= m - 1;
      nbr[atomicAdd(&cnt, 1)] = w * 32 + b;
    }
  }
  __syncthreads();
  int nc = cnt;
  for (int w = threadIdx.x; w < Wd; w += 128) {
    unsigned acc = 0;
    for (int q = 0; q < nc; q++) acc |= in[(size_t)nbr[q] * Wd + w];
    out[(size_t)i * Wd + w] = acc;
  }
}

// holes = ~bits, tail bits masked
__global__ void complement_bits_kernel(const unsigned* __restrict__ in,
                                       unsigned* __restrict__ out, int Wd, int K,
                                       int M) {
  int total = M * Wd;
  for (int idx = blockIdx.x * 256 + threadIdx.x; idx < total;
       idx += gridDim.x * 256) {
    int w = idx % Wd;
    unsigned v = ~in[idx];
    int valid = K - w * 32;
    unsigned mask = valid >= 32 ? 0xffffffffu : (valid <= 0 ? 0u : ((1u << valid) - 1u));
    out[idx] = v & mask;
  }
}

// ---- feature GEMM: C[M x 64] = rs? .* (A[M x K] @ B[K x 64]) + bias?, relu? ----
// 4 rows/block (grid ~M/4) for occupancy; B chunk staged in LDS.
__global__ void gemm_feat_kernel(const float* __restrict__ A, int lda,
                                 const float* __restrict__ B,
                                 const float* __restrict__ rowscale,
                                 const float* __restrict__ bias,
                                 float* __restrict__ C, int M, int K, int relu) {
  __shared__ float Bs[64][65];
  __shared__ float As[4][64];
  int lane = threadIdx.x & 63, wv = threadIdx.x >> 6;
  int row = blockIdx.x * 4 + wv;
  float acc = 0.f;
  for (int k0 = 0; k0 < K; k0 += 64) {
    for (int l = threadIdx.x; l < 64 * 64; l += 256) {
      int kk = l >> 6, ff = l & 63;
      int gk = k0 + kk;
      Bs[kk][ff] = gk < K ? B[(size_t)gk * 64 + ff] : 0.f;
    }
    int gk = k0 + lane;
    As[wv][lane] = (row < M && gk < K) ? A[(size_t)row * lda + gk] : 0.f;
    __syncthreads();
    if (row < M) {
#pragma unroll 16
      for (int kk = 0; kk < 64; kk++) acc += As[wv][kk] * Bs[kk][lane];
    }
    __syncthreads();
  }
  if (row < M) {
    float v = acc;
    if (rowscale) v *= rowscale[row];
    if (bias) v += bias[lane];
    if (relu) v = fmaxf(v, 0.f);
    C[(size_t)row * 64 + lane] = v;
  }
}

// colsum[f] = sum_r X[r][f], deterministic 2-stage
__global__ void colsum_part_kernel(const float* __restrict__ X, int K,
                                   float* part) {
  __shared__ float red[4][64];
  int lane = threadIdx.x & 63, wv = threadIdx.x >> 6;
  int r0 = blockIdx.x * 64;
  float a = 0.f;
  for (int i = wv; i < 64; i += 4) {
    int r = r0 + i;
    if (r < K) a += X[(size_t)r * 64 + lane];
  }
  red[wv][lane] = a;
  __syncthreads();
  if (!wv)
    part[(size_t)blockIdx.x * 64 + lane] =
        red[0][lane] + red[1][lane] + red[2][lane] + red[3][lane];
}

__global__ void colsum_final_kernel(const float* __restrict__ part, int G,
                                    float* csum) {
  __shared__ float red[4][64];
  int lane = threadIdx.x & 63, wv = threadIdx.x >> 6;
  float a = 0.f;
  for (int g = wv; g < G; g += 4) a += part[(size_t)g * 64 + lane];
  red[wv][lane] = a;
  __syncthreads();
  if (!wv)
    csum[lane] = red[0][lane] + red[1][lane] + red[2][lane] + red[3][lane];
}

// out[M x 500] = Y[M x 64] @ B[64 x 500] + bias   (one row per block)
__global__ void gemm_wide_kernel(const float* __restrict__ Y,
                                 const float* __restrict__ B,
                                 const float* __restrict__ bias,
                                 float* __restrict__ C, int M) {
  __shared__ float ys[64];
  int r = blockIdx.x;
  if (threadIdx.x < 64) ys[threadIdx.x] = Y[(size_t)r * 64 + threadIdx.x];
  __syncthreads();
  int c = threadIdx.x;
  if (c < FIN) {
    float acc = bias[c];
#pragma unroll 16
    for (int k = 0; k < 64; k++) acc += ys[k] * B[k * FIN + c];
    C[(size_t)r * FIN + c] = acc;
  }
}

// ---------------------------------------------------------------------------

extern "C" void kernel_launch(void* const* d_in, const int* in_sizes, int n_in,
                              void* d_out, int out_size, void* d_ws, size_t ws_size,
                              hipStream_t stream) {
  const float* x      = (const float*)d_in[0];
  const float* w1     = (const float*)d_in[1];
  const float* b1     = (const float*)d_in[2];
  const float* w2     = (const float*)d_in[3];
  const float* b2     = (const float*)d_in[4];
  const float* w3     = (const float*)d_in[5];
  const float* b3     = (const float*)d_in[6];
  const float* p1wrel = (const float*)d_in[7];
  const float* p1brel = (const float*)d_in[8];
  const float* p1wroot= (const float*)d_in[9];
  const float* p2wrel = (const float*)d_in[10];
  const float* p2brel = (const float*)d_in[11];
  const float* p2wroot= (const float*)d_in[12];
  const float* p3wrel = (const float*)d_in[13];
  const float* p3brel = (const float*)d_in[14];
  const float* p3wroot= (const float*)d_in[15];
  const float* u0w    = (const float*)d_in[16];
  const float* u0b    = (const float*)d_in[17];
  const float* u1w    = (const float*)d_in[18];
  const float* u1b    = (const float*)d_in[19];
  const float* u2w    = (const float*)d_in[20];
  const float* u2b    = (const float*)d_in[21];
  const int*   ei     = (const int*)d_in[22];
  float* out = (float*)d_out;

  char* wp = (char*)d_ws;
  auto alloc = [&](size_t bytes) -> void* {
    void* p = (void*)wp;
    wp += (bytes + 255) & ~(size_t)255;
    return p;
  };
  unsigned* A0b  = (unsigned*)alloc((size_t)NN  * W0 * 4);
  unsigned* A1b  = (unsigned*)alloc((size_t)KK1 * W1 * 4);
  unsigned* A1ab = (unsigned*)alloc((size_t)KK1 * W1 * 4);
  unsigned* A2b  = (unsigned*)alloc((size_t)KK2 * W2 * 4);
  unsigned* A2ab = (unsigned*)alloc((size_t)KK2 * W2 * 4);
  unsigned* H2b  = (unsigned*)alloc((size_t)KK2 * W2 * 4);
  float* dis0 = (float*)alloc((size_t)NN * 4);
  float* dis1 = (float*)alloc((size_t)KK1 * 4);
  float* dis2 = (float*)alloc((size_t)KK2 * 4);
  float* xw   = (float*)alloc((size_t)NN * 64 * 4);
  float* x1   = (float*)alloc((size_t)NN * 64 * 4);
  float* x1p  = (float*)alloc((size_t)KK1 * 64 * 4);
  float* x2   = (float*)alloc((size_t)KK1 * 64 * 4);
  float* x2p  = (float*)alloc((size_t)KK2 * 64 * 4);
  float* x3   = (float*)alloc((size_t)KK2 * 64 * 4);
  float* x3p  = (float*)alloc((size_t)KK3 * 64 * 4);
  float* zd2  = (float*)alloc((size_t)KK2 * 64 * 4);
  float* zd1  = (float*)alloc((size_t)KK1 * 64 * 4);
  float* up   = (float*)alloc((size_t)NN * 64 * 4);
  float* y0   = (float*)alloc((size_t)NN * 64 * 4);
  float* tvec = (float*)alloc((size_t)NN * 4);
  float* rvec = (float*)alloc((size_t)NN * 4);
  float* svec = (float*)alloc((size_t)NN * 4);
  float* vals = (float*)alloc((size_t)NN * 4);
  float* part = (float*)alloc((size_t)64 * 64 * 4);
  float* csum = (float*)alloc((size_t)64 * 4);
  float* tot  = (float*)alloc((size_t)4);
  int* rank  = (int*)alloc((size_t)NN * 4);
  int* perm1 = (int*)alloc((size_t)KK1 * 4);
  int* perm2 = (int*)alloc((size_t)KK2 * 4);
  int* perm3 = (int*)alloc((size_t)KK3 * 4);

  auto fill = [&](void* p, long n_floats) {
    long n4 = (n_floats + 3) / 4;
    int grid = (int)min((long)2048, (n4 + 255) / 256);
    fill4_kernel<<<grid, 256, 0, stream>>>((float4*)p, n4);
  };

  // ---- A0 bitset + dis0 ----
  fill(A0b, (long)NN * W0);
  scatter_bits_kernel<<<(EE + 255) / 256, 256, 0, stream>>>(A0b, ei);
  popcnt_dis_kernel<<<NN / 4, 256, 0, stream>>>(A0b, W0, dis0, NN);

  // ---- level 1 ----
  gemm_feat_kernel<<<NN / 4, 256, 0, stream>>>(x, FIN, w1, dis0, nullptr, xw, NN, FIN, 0);
  spmm_bits_kernel<<<NN / 4, 256, 0, stream>>>(A0b, W0, xw, nullptr, dis0, b1, x1, NN, 0);
  rowdot2_kernel<<<NN / 4, 256, 0, stream>>>(x1, p1wrel, p1wroot, tvec, rvec, NN);
  matvec_bits_kernel<<<NN / 4, 256, 0, stream>>>(A0b, W0, tvec, rvec, p1brel, nullptr, svec, NN);
  fill(rank, NN);
  topk_count_kernel<<<dim3((NN + 255) / 256, (NN + 511) / 512), 256, 0, stream>>>(svec, NN, rank);
  topk_place_kernel<<<(NN + 255) / 256, 256, 0, stream>>>(svec, rank, NN, KK1, perm1, vals);
  subgraph_bits_kernel<<<KK1, 256, 0, stream>>>(A0b, W0, perm1, KK1, W1, A1b);
  augment_or_kernel<<<KK1, 128, 0, stream>>>(A1b, A1ab, W1);
  popcnt_dis_kernel<<<(KK1 + 3) / 4, 256, 0, stream>>>(A1ab, W1, dis1, KK1);
  gather_gate_kernel<<<(KK1 + 3) / 4, 256, 0, stream>>>(x1, perm1, vals, dis1, x1p, KK1);

  // ---- level 2 ----
  gemm_feat_kernel<<<(KK1 + 3) / 4, 256, 0, stream>>>(x1p, 64, w2, nullptr, nullptr, xw, KK1, 64, 0);
  spmm_bits_kernel<<<(KK1 + 3) / 4, 256, 0, stream>>>(A1ab, W1, xw, nullptr, dis1, b2, x2, KK1, 0);
  rowdot2_kernel<<<(KK1 + 3) / 4, 256, 0, stream>>>(x2, p2wrel, p2wroot, tvec, rvec, KK1);
  matvec_bits_kernel<<<(KK1 + 3) / 4, 256, 0, stream>>>(A1ab, W1, tvec, rvec, p2brel, nullptr, svec, KK1);
  fill(rank, KK1);
  topk_count_kernel<<<dim3((KK1 + 255) / 256, (KK1 + 511) / 512), 256, 0, stream>>>(svec, KK1, rank);
  topk_place_kernel<<<(KK1 + 255) / 256, 256, 0, stream>>>(svec, rank, KK1, KK2, perm2, vals);
  subgraph_bits_kernel<<<KK2, 256, 0, stream>>>(A1ab, W1, perm2, KK2, W2, A2b);
  augment_or_kernel<<<KK2, 128, 0, stream>>>(A2b, A2ab, W2);
  popcnt_dis_kernel<<<(KK2 + 3) / 4, 256, 0, stream>>>(A2ab, W2, dis2, KK2);
  complement_bits_kernel<<<256, 256, 0, stream>>>(A2ab, H2b, W2, KK2, KK2);
  gather_gate_kernel<<<(KK2 + 3) / 4, 256, 0, stream>>>(x2, perm2, vals, dis2, x2p, KK2);

  // ---- level 3 (A2a ~fully dense -> complement) ----
  gemm_feat_kernel<<<(KK2 + 3) / 4, 256, 0, stream>>>(x2p, 64, w3, nullptr, nullptr, xw, KK2, 64, 0);
  colsum_part_kernel<<<(KK2 + 63) / 64, 256, 0, stream>>>(xw, KK2, part);
  colsum_final_kernel<<<1, 256, 0, stream>>>(part, (KK2 + 63) / 64, csum);
  spmm_bits_kernel<<<(KK2 + 3) / 4, 256, 0, stream>>>(H2b, W2, xw, csum, dis2, b3, x3, KK2, 0);
  rowdot2_kernel<<<(KK2 + 3) / 4, 256, 0, stream>>>(x3, p3wrel, p3wroot, tvec, rvec, KK2);
  vec_total_kernel<<<1, 256, 0, stream>>>(tvec, KK2, tot);
  matvec_bits_kernel<<<(KK2 + 3) / 4, 256, 0, stream>>>(H2b, W2, tvec, rvec, p3brel, tot, svec, KK2);
  fill(rank, KK2);
  topk_count_kernel<<<dim3((KK2 + 255) / 256, (KK2 + 511) / 512), 256, 0, stream>>>(svec, KK2, rank);
  topk_place_kernel<<<(KK2 + 255) / 256, 256, 0, stream>>>(svec, rank, KK2, KK3, perm3, vals);
  gather_gate_kernel<<<(KK3 + 3) / 4, 256, 0, stream>>>(x3, perm3, vals, nullptr, x3p, KK3);

  // ---- decoder ----
  fill(up, (long)KK2 * 64);
  scatter_rows_kernel<<<(KK3 + 3) / 4, 256, 0, stream>>>(x3p, perm3, dis2, up, KK3);
  gemm_feat_kernel<<<(KK2 + 3) / 4, 256, 0, stream>>>(up, 64, u0w, nullptr, nullptr, xw, KK2, 64, 0);
  colsum_part_kernel<<<(KK2 + 63) / 64, 256, 0, stream>>>(xw, KK2, part);
  colsum_final_kernel<<<1, 256, 0, stream>>>(part, (KK2 + 63) / 64, csum);
  spmm_bits_kernel<<<(KK2 + 3) / 4, 256, 0, stream>>>(H2b, W2, xw, csum, dis2, u0b, zd2, KK2, 1);

  fill(up, (long)KK1 * 64);
  scatter_rows_kernel<<<(KK2 + 3) / 4, 256, 0, stream>>>(zd2, perm2, dis1, up, KK2);
  gemm_feat_kernel<<<(KK1 + 3) / 4, 256, 0, stream>>>(up, 64, u1w, nullptr, nullptr, xw, KK1, 64, 0);
  spmm_bits_kernel<<<(KK1 + 3) / 4, 256, 0, stream>>>(A1ab, W1, xw, nullptr, dis1, u1b, zd1, KK1, 1);

  fill(up, (long)NN * 64);
  scatter_rows_kernel<<<(KK1 + 3) / 4, 256, 0, stream>>>(zd1, perm1, dis0, up, KK1);
  // final GCN reassociated: out = (dis0 .* (A0 @ (dis0 .* up))) @ u2w + u2b
  spmm_bits_kernel<<<NN / 4, 256, 0, stream>>>(A0b, W0, up, nullptr, dis0, nullptr, y0, NN, 0);
  gemm_wide_kernel<<<NN, 512, 0, stream>>>(y0, u2w, u2b, out, NN);
}

// Round 3
// 402.921 us; speedup vs baseline: 7.6327x; 1.5919x over previous
//
#include <hip/hip_runtime.h>

// ---------------------------------------------------------------------------
// Graph U-Net (GCN + SAGPool encoder / unpool decoder) on MI355X, fp32.
// Round 3: SpMM via LDS neighbor-list extraction + unrolled gather (breaks the
// serial ffs chain that made each gather cost ~865 cyc). Heavy fusion:
//  - score rowdots fused into spmm epilogue
//  - popcnt(dis) + complement(holes) fused into augment epilogue
//  - gather*tanh*dis fused into the feature GEMM (x1p/x2p/x3p never stored)
//  - decoder scatter fused into spmm's store (zd1/zd2 never stored)
// ---------------------------------------------------------------------------

constexpr int NN  = 4096;
constexpr int EE  = 65536;
constexpr int FIN = 500;
constexpr int KK1 = 3277, KK2 = 2622, KK3 = 2098;
constexpr int W0  = 128;               // words per A0 bit-row
constexpr int W1  = (KK1 + 31) / 32;   // 103
constexpr int W2  = (KK2 + 31) / 32;   // 82
constexpr int CAP = 2048;              // max tracked degree (theory max ~1300)

// -------------------------------- utility ----------------------------------

__global__ void fill4_kernel(float4* p, long n4) {
  long i = (long)blockIdx.x * blockDim.x + threadIdx.x;
  long stride = (long)gridDim.x * blockDim.x;
  float4 z = make_float4(0.f, 0.f, 0.f, 0.f);
  for (; i < n4; i += stride) p[i] = z;
}

__global__ void scatter_bits_kernel(unsigned* Ab, const int* __restrict__ ei) {
  int e = blockIdx.x * 256 + threadIdx.x;
  if (e < EE) {
    int src = ei[e], dst = ei[EE + e];
    atomicOr(&Ab[(size_t)dst * W0 + (src >> 5)], 1u << (src & 31));
  }
  if (e < NN) atomicOr(&Ab[(size_t)e * W0 + (e >> 5)], 1u << (e & 31));
}

__global__ void popcnt_dis_kernel(const unsigned* __restrict__ bits, int Wd,
                                  float* dis, int M) {
  int lane = threadIdx.x & 63;
  int row = blockIdx.x * 4 + (threadIdx.x >> 6);
  if (row >= M) return;
  const unsigned* rb = bits + (size_t)row * Wd;
  int c = 0;
  for (int w = lane; w < Wd; w += 64) c += __popc(rb[w]);
  for (int off = 32; off; off >>= 1) c += __shfl_down(c, off, 64);
  if (!lane) dis[row] = c > 0 ? rsqrtf((float)c) : 0.f;
}

// ---- SpMM over bitset adjacency, neighbor-list staged in LDS --------------
// add mode (base==null): v = rs[row] * (bits_row @ B) + bias
// sub mode:              v = rs[row] * (base - bits_row @ B) + bias
// then optional relu; store C[row] or scattered C[perm[row]] * sscale[perm[row]];
// optional fused score dots: tvec[row]=v.wrel, rvec[row]=v.wroot
__global__ void spmm_nbr_kernel(const unsigned* __restrict__ bits, int Wd,
                                const float* __restrict__ B,
                                const float* __restrict__ base,
                                const float* __restrict__ rowscale,
                                const float* __restrict__ bias,
                                const float* __restrict__ wrel,
                                const float* __restrict__ wroot,
                                float* __restrict__ tvec, float* __restrict__ rvec,
                                const int* __restrict__ sperm,
                                const float* __restrict__ sscale,
                                float* __restrict__ C, int M, int relu) {
  __shared__ int nbr[4][CAP];
  __shared__ int cnt[4];
  int lane = threadIdx.x & 63, wv = threadIdx.x >> 6;
  int row = blockIdx.x * 4 + wv;
  if (threadIdx.x < 4) cnt[threadIdx.x] = 0;
  __syncthreads();
  if (row < M) {
    const unsigned* rb = bits + (size_t)row * Wd;
    for (int w = lane; w < Wd; w += 64) {
      unsigned m = rb[w];
      while (m) {
        int b = __ffs(m) - 1;
        m &= m - 1;
        int idx = atomicAdd(&cnt[wv], 1);
        if (idx < CAP) nbr[wv][idx] = (w << 5) + b;
      }
    }
  }
  __syncthreads();
  if (row >= M) return;
  int nc = cnt[wv];
  float acc;
  if (nc <= CAP) {
    const int* lst = nbr[wv];
    float a0 = 0.f, a1 = 0.f, a2 = 0.f, a3 = 0.f;
    int q = 0;
    for (; q + 8 <= nc; q += 8) {
      int j0 = lst[q],     j1 = lst[q + 1], j2 = lst[q + 2], j3 = lst[q + 3];
      int j4 = lst[q + 4], j5 = lst[q + 5], j6 = lst[q + 6], j7 = lst[q + 7];
      float v0 = B[(size_t)j0 * 64 + lane], v1 = B[(size_t)j1 * 64 + lane];
      float v2 = B[(size_t)j2 * 64 + lane], v3 = B[(size_t)j3 * 64 + lane];
      float v4 = B[(size_t)j4 * 64 + lane], v5 = B[(size_t)j5 * 64 + lane];
      float v6 = B[(size_t)j6 * 64 + lane], v7 = B[(size_t)j7 * 64 + lane];
      a0 += v0 + v4; a1 += v1 + v5; a2 += v2 + v6; a3 += v3 + v7;
    }
    for (; q < nc; q++) a0 += B[(size_t)lst[q] * 64 + lane];
    acc = (a0 + a1) + (a2 + a3);
  } else {  // overflow fallback (not expected): serial bitscan
    const unsigned* rb = bits + (size_t)row * Wd;
    float a = 0.f;
    for (int w = 0; w < Wd; w++) {
      unsigned m = rb[w];
      while (m) {
        int b = __ffs(m) - 1;
        m &= m - 1;
        a += B[(size_t)((w << 5) + b) * 64 + lane];
      }
    }
    acc = a;
  }
  if (base) acc = base[lane] - acc;
  float v = acc * rowscale[row];
  if (bias) v += bias[lane];
  if (relu) v = fmaxf(v, 0.f);
  if (sperm) {
    int p = sperm[row];
    C[(size_t)p * 64 + lane] = v * sscale[p];
  } else {
    C[(size_t)row * 64 + lane] = v;
  }
  if (wrel) {
    float t1 = v * wrel[lane], t2 = v * wroot[lane];
    for (int off = 32; off; off >>= 1) {
      t1 += __shfl_down(t1, off, 64);
      t2 += __shfl_down(t2, off, 64);
    }
    if (!lane) { tvec[row] = t1; rvec[row] = t2; }
  }
}

// s[row] = (total? total-sum : sum){t[j] : j in bits(row)} + brel + rv[row]
__global__ void matvec_bits_kernel(const unsigned* __restrict__ bits, int Wd,
                                   const float* __restrict__ t,
                                   const float* __restrict__ rv,
                                   const float* __restrict__ brel,
                                   const float* __restrict__ total,
                                   float* __restrict__ s, int M) {
  int lane = threadIdx.x & 63;
  int row = blockIdx.x * 4 + (threadIdx.x >> 6);
  if (row >= M) return;
  const unsigned* rb = bits + (size_t)row * Wd;
  float acc = 0.f;
  for (int w = lane; w < Wd; w += 64) {
    unsigned m = rb[w];
    while (m) {
      int b = __ffs(m) - 1;
      m &= m - 1;
      acc += t[(w << 5) + b];
    }
  }
  for (int off = 32; off; off >>= 1) acc += __shfl_down(acc, off, 64);
  if (!lane) {
    float r0 = total ? total[0] - acc : acc;
    s[row] = r0 + brel[0] + rv[row];
  }
}

__global__ void vec_total_kernel(const float* __restrict__ t, int n, float* tot) {
  __shared__ float red[256];
  float a = 0.f;
  for (int i = threadIdx.x; i < n; i += 256) a += t[i];
  red[threadIdx.x] = a;
  __syncthreads();
  for (int o = 128; o; o >>= 1) {
    if (threadIdx.x < o) red[threadIdx.x] += red[threadIdx.x + o];
    __syncthreads();
  }
  if (!threadIdx.x) tot[0] = red[0];
}

// ---- top-k (exact lax.top_k order), 2D-split rank count ----
__global__ void topk_count_kernel(const float* __restrict__ s, int n, int* rank) {
  __shared__ float sh[512];
  int j0 = blockIdx.y * 512;
  for (int j = threadIdx.x; j < 512; j += 256) {
    int gj = j0 + j;
    sh[j] = gj < n ? s[gj] : 0.f;
  }
  __syncthreads();
  int i = blockIdx.x * 256 + threadIdx.x;
  if (i >= n) return;
  float si = s[i];
  int jmax = min(512, n - j0);
  int cnt = 0;
  for (int j = 0; j < jmax; j++) {
    float sj = sh[j];
    int gj = j0 + j;
    cnt += (sj > si || (sj == si && gj < i)) ? 1 : 0;
  }
  if (cnt) atomicAdd(&rank[i], cnt);
}

__global__ void topk_place_kernel(const float* __restrict__ s,
                                  const int* __restrict__ rank, int n, int k,
                                  int* perm, float* vals) {
  int i = blockIdx.x * 256 + threadIdx.x;
  if (i >= n) return;
  int rk = rank[i];
  if (rk < k) { perm[rk] = i; vals[rk] = s[i]; }
}

// up[perm[r]] = X[perm[r]] * tanh(vals[r]) * scale[perm[r]]
__global__ void scatter_gate_kernel(const float* __restrict__ X,
                                    const int* __restrict__ perm,
                                    const float* __restrict__ vals,
                                    const float* __restrict__ scale,
                                    float* up, int k) {
  int r = blockIdx.x * 4 + (threadIdx.x >> 6);
  int f = threadIdx.x & 63;
  if (r < k) {
    int p = perm[r];
    up[(size_t)p * 64 + f] = X[(size_t)p * 64 + f] * tanhf(vals[r]) * scale[p];
  }
}

// out[r] bits = { Ab[perm[r]] bit perm[c] : c in [0,K) }
__global__ void subgraph_bits_kernel(const unsigned* __restrict__ Ab, int WdIn,
                                     const int* __restrict__ perm, int K, int WdOut,
                                     unsigned* __restrict__ out) {
  __shared__ unsigned rowb[128];
  int r = blockIdx.x;
  const unsigned* src = Ab + (size_t)perm[r] * WdIn;
  for (int w = threadIdx.x; w < WdIn; w += 256) rowb[w] = src[w];
  __syncthreads();
  unsigned* ob = out + (size_t)r * WdOut;
  for (int c0 = 0; c0 < WdOut * 32; c0 += 256) {
    int c = c0 + threadIdx.x;
    bool pred = false;
    if (c < K) {
      int pc = perm[c];
      pred = (rowb[pc >> 5] >> (pc & 31)) & 1u;
    }
    unsigned long long m = __ballot(pred);
    if ((threadIdx.x & 63) == 0) {
      int wb = (c0 >> 5) + ((threadIdx.x >> 6) << 1);
      if (wb < WdOut)     ob[wb]     = (unsigned)m;
      if (wb + 1 < WdOut) ob[wb + 1] = (unsigned)(m >> 32);
    }
  }
}

// row i of A^2>0: OR of in_row[j] over set bits j of in_row[i].
// Fused epilogue: dis[i] = rsqrt(popcount); write row (out) and/or complement
// with tail mask (holes).
__global__ void augment_or_kernel(const unsigned* __restrict__ in,
                                  unsigned* __restrict__ out,
                                  unsigned* __restrict__ holes,
                                  float* __restrict__ dis, int Wd, int K) {
  __shared__ unsigned roww[128];
  __shared__ int nbr[CAP];
  __shared__ int cnt;
  __shared__ int pcred[128];
  int i = blockIdx.x;
  if (threadIdx.x == 0) cnt = 0;
  const unsigned* rin = in + (size_t)i * Wd;
  for (int w = threadIdx.x; w < Wd; w += 128) roww[w] = rin[w];
  __syncthreads();
  for (int w = threadIdx.x; w < Wd; w += 128) {
    unsigned m = roww[w];
    while (m) {
      int b = __ffs(m) - 1;
      m &= m - 1;
      int idx = atomicAdd(&cnt, 1);
      if (idx < CAP) nbr[idx] = w * 32 + b;
    }
  }
  __syncthreads();
  int nc = min(cnt, CAP);   // cnt>CAP cannot happen (deg<=K<=3277? guarded by CAP=2048; theory max ~1300)
  int pc = 0;
  for (int w = threadIdx.x; w < Wd; w += 128) {
    unsigned a0 = 0, a1 = 0, a2 = 0, a3 = 0;
    int q = 0;
    for (; q + 4 <= nc; q += 4) {
      a0 |= in[(size_t)nbr[q] * Wd + w];
      a1 |= in[(size_t)nbr[q + 1] * Wd + w];
      a2 |= in[(size_t)nbr[q + 2] * Wd + w];
      a3 |= in[(size_t)nbr[q + 3] * Wd + w];
    }
    for (; q < nc; q++) a0 |= in[(size_t)nbr[q] * Wd + w];
    unsigned acc = (a0 | a1) | (a2 | a3);
    pc += __popc(acc);
    if (out) out[(size_t)i * Wd + w] = acc;
    if (holes) {
      int valid = K - w * 32;
      unsigned mask = valid >= 32 ? 0xffffffffu : ((1u << valid) - 1u);
      holes[(size_t)i * Wd + w] = ~acc & mask;
    }
  }
  pcred[threadIdx.x] = pc;
  __syncthreads();
  for (int o = 64; o; o >>= 1) {
    if (threadIdx.x < o) pcred[threadIdx.x] += pcred[threadIdx.x + o];
    __syncthreads();
  }
  if (!threadIdx.x) dis[i] = pcred[0] > 0 ? rsqrtf((float)pcred[0]) : 0.f;
}

// ---- feature GEMM, K arbitrary (used for x @ w1, K=500) ----
__global__ void gemm_feat_kernel(const float* __restrict__ A, int lda,
                                 const float* __restrict__ B,
                                 const float* __restrict__ rowscale,
                                 float* __restrict__ C, int M, int K) {
  __shared__ float Bs[64][65];
  __shared__ float As[4][64];
  int lane = threadIdx.x & 63, wv = threadIdx.x >> 6;
  int row = blockIdx.x * 4 + wv;
  float acc = 0.f;
  for (int k0 = 0; k0 < K; k0 += 64) {
    for (int l = threadIdx.x; l < 64 * 64; l += 256) {
      int kk = l >> 6, ff = l & 63;
      int gk = k0 + kk;
      Bs[kk][ff] = gk < K ? B[(size_t)gk * 64 + ff] : 0.f;
    }
    int gk = k0 + lane;
    As[wv][lane] = (row < M && gk < K) ? A[(size_t)row * lda + gk] : 0.f;
    __syncthreads();
    if (row < M) {
#pragma unroll 16
      for (int kk = 0; kk < 64; kk++) acc += As[wv][kk] * Bs[kk][lane];
    }
    __syncthreads();
  }
  if (row < M) {
    float v = acc;
    if (rowscale) v *= rowscale[row];
    C[(size_t)row * 64 + lane] = v;
  }
}

// ---- K=64 feature GEMM; optional gathered A-row: X[perm[r]]*tanh(vals[r])*gs[r]
__global__ void gemm_k64_kernel(const float* __restrict__ X,
                                const float* __restrict__ B,
                                const int* __restrict__ perm,
                                const float* __restrict__ vals,
                                const float* __restrict__ gscale,
                                float* __restrict__ C, int M) {
  __shared__ float Bs[64][65];
  __shared__ float As[4][64];
  int lane = threadIdx.x & 63, wv = threadIdx.x >> 6;
  int row = blockIdx.x * 4 + wv;
  for (int l = threadIdx.x; l < 64 * 64; l += 256) Bs[l >> 6][l & 63] = B[l];
  if (row < M) {
    int src = row;
    float g = 1.f;
    if (perm) {
      src = perm[row];
      g = tanhf(vals[row]) * gscale[row];
    }
    As[wv][lane] = X[(size_t)src * 64 + lane] * g;
  }
  __syncthreads();
  if (row < M) {
    float acc = 0.f;
#pragma unroll 16
    for (int k = 0; k < 64; k++) acc += As[wv][k] * Bs[k][lane];
    C[(size_t)row * 64 + lane] = acc;
  }
}

// colsum[f] = sum_r X[r][f], deterministic 2-stage
__global__ void colsum_part_kernel(const float* __restrict__ X, int K,
                                   float* part) {
  __shared__ float red[4][64];
  int lane = threadIdx.x & 63, wv = threadIdx.x >> 6;
  int r0 = blockIdx.x * 64;
  float a = 0.f;
  for (int i = wv; i < 64; i += 4) {
    int r = r0 + i;
    if (r < K) a += X[(size_t)r * 64 + lane];
  }
  red[wv][lane] = a;
  __syncthreads();
  if (!wv)
    part[(size_t)blockIdx.x * 64 + lane] =
        red[0][lane] + red[1][lane] + red[2][lane] + red[3][lane];
}

__global__ void colsum_final_kernel(const float* __restrict__ part, int G,
                                    float* csum) {
  __shared__ float red[4][64];
  int lane = threadIdx.x & 63, wv = threadIdx.x >> 6;
  float a = 0.f;
  for (int g = wv; g < G; g += 4) a += part[(size_t)g * 64 + lane];
  red[wv][lane] = a;
  __syncthreads();
  if (!wv)
    csum[lane] = red[0][lane] + red[1][lane] + red[2][lane] + red[3][lane];
}

// out[M x 500] = Y[M x 64] @ B[64 x 500] + bias   (4 rows per block)
__global__ void gemm_wide4_kernel(const float* __restrict__ Y,
                                  const float* __restrict__ B,
                                  const float* __restrict__ bias,
                                  float* __restrict__ C, int M) {
  __shared__ float Ys[4][64];
  int r0 = blockIdx.x * 4;
  {
    int l = threadIdx.x;           // 256 threads load 4x64
    int r = l >> 6, k = l & 63;
    Ys[r][k] = (r0 + r < M) ? Y[(size_t)(r0 + r) * 64 + k] : 0.f;
  }
  __syncthreads();
  for (int c = threadIdx.x; c < FIN; c += 256) {
    float bv0 = bias[c];
    float a0 = bv0, a1 = bv0, a2 = bv0, a3 = bv0;
#pragma unroll 16
    for (int k = 0; k < 64; k++) {
      float bv = B[k * FIN + c];
      a0 += Ys[0][k] * bv;
      a1 += Ys[1][k] * bv;
      a2 += Ys[2][k] * bv;
      a3 += Ys[3][k] * bv;
    }
    if (r0 + 0 < M) C[(size_t)(r0 + 0) * FIN + c] = a0;
    if (r0 + 1 < M) C[(size_t)(r0 + 1) * FIN + c] = a1;
    if (r0 + 2 < M) C[(size_t)(r0 + 2) * FIN + c] = a2;
    if (r0 + 3 < M) C[(size_t)(r0 + 3) * FIN + c] = a3;
  }
}

// ---------------------------------------------------------------------------

extern "C" void kernel_launch(void* const* d_in, const int* in_sizes, int n_in,
                              void* d_out, int out_size, void* d_ws, size_t ws_size,
                              hipStream_t stream) {
  const float* x      = (const float*)d_in[0];
  const float* w1     = (const float*)d_in[1];
  const float* b1     = (const float*)d_in[2];
  const float* w2     = (const float*)d_in[3];
  const float* b2     = (const float*)d_in[4];
  const float* w3     = (const float*)d_in[5];
  const float* b3     = (const float*)d_in[6];
  const float* p1wrel = (const float*)d_in[7];
  const float* p1brel = (const float*)d_in[8];
  const float* p1wroot= (const float*)d_in[9];
  const float* p2wrel = (const float*)d_in[10];
  const float* p2brel = (const float*)d_in[11];
  const float* p2wroot= (const float*)d_in[12];
  const float* p3wrel = (const float*)d_in[13];
  const float* p3brel = (const float*)d_in[14];
  const float* p3wroot= (const float*)d_in[15];
  const float* u0w    = (const float*)d_in[16];
  const float* u0b    = (const float*)d_in[17];
  const float* u1w    = (const float*)d_in[18];
  const float* u1b    = (const float*)d_in[19];
  const float* u2w    = (const float*)d_in[20];
  const float* u2b    = (const float*)d_in[21];
  const int*   ei     = (const int*)d_in[22];
  float* out = (float*)d_out;

  char* wp = (char*)d_ws;
  auto alloc = [&](size_t bytes) -> void* {
    void* p = (void*)wp;
    wp += (bytes + 255) & ~(size_t)255;
    return p;
  };
  unsigned* A0b  = (unsigned*)alloc((size_t)NN  * W0 * 4);
  unsigned* A1b  = (unsigned*)alloc((size_t)KK1 * W1 * 4);
  unsigned* A1ab = (unsigned*)alloc((size_t)KK1 * W1 * 4);
  unsigned* A2b  = (unsigned*)alloc((size_t)KK2 * W2 * 4);
  unsigned* H2b  = (unsigned*)alloc((size_t)KK2 * W2 * 4);
  float* dis0 = (float*)alloc((size_t)NN * 4);
  float* dis1 = (float*)alloc((size_t)KK1 * 4);
  float* dis2 = (float*)alloc((size_t)KK2 * 4);
  float* xw   = (float*)alloc((size_t)NN * 64 * 4);
  float* x1   = (float*)alloc((size_t)NN * 64 * 4);
  float* x2   = (float*)alloc((size_t)KK1 * 64 * 4);
  float* x3   = (float*)alloc((size_t)KK2 * 64 * 4);
  float* up0  = (float*)alloc((size_t)KK2 * 64 * 4);
  float* up1  = (float*)alloc((size_t)KK1 * 64 * 4);
  float* up2  = (float*)alloc((size_t)NN * 64 * 4);
  float* y0   = (float*)alloc((size_t)NN * 64 * 4);
  float* tvec = (float*)alloc((size_t)NN * 4);
  float* rvec = (float*)alloc((size_t)NN * 4);
  float* svec = (float*)alloc((size_t)NN * 4);
  float* vals = (float*)alloc((size_t)NN * 4);
  float* part = (float*)alloc((size_t)64 * 64 * 4);
  float* csum = (float*)alloc((size_t)64 * 4);
  float* tot  = (float*)alloc((size_t)4);
  int* rank  = (int*)alloc((size_t)NN * 4);
  int* perm1 = (int*)alloc((size_t)KK1 * 4);
  int* perm2 = (int*)alloc((size_t)KK2 * 4);
  int* perm3 = (int*)alloc((size_t)KK3 * 4);

  auto fill = [&](void* p, long n_floats) {
    long n4 = (n_floats + 3) / 4;
    int grid = (int)min((long)2048, (n4 + 255) / 256);
    fill4_kernel<<<grid, 256, 0, stream>>>((float4*)p, n4);
  };

  // ---- zero-init buffers that receive scattered writes ----
  fill(A0b, (long)NN * W0);
  fill(up0, (long)KK2 * 64);
  fill(up1, (long)KK1 * 64);
  fill(up2, (long)NN * 64);

  // ---- A0 bitset + dis0 ----
  scatter_bits_kernel<<<(EE + 255) / 256, 256, 0, stream>>>(A0b, ei);
  popcnt_dis_kernel<<<NN / 4, 256, 0, stream>>>(A0b, W0, dis0, NN);

  // ---- level 1 ----
  gemm_feat_kernel<<<NN / 4, 256, 0, stream>>>(x, FIN, w1, dis0, xw, NN, FIN);
  spmm_nbr_kernel<<<NN / 4, 256, 0, stream>>>(A0b, W0, xw, nullptr, dis0, b1,
      p1wrel, p1wroot, tvec, rvec, nullptr, nullptr, x1, NN, 0);
  matvec_bits_kernel<<<NN / 4, 256, 0, stream>>>(A0b, W0, tvec, rvec, p1brel, nullptr, svec, NN);
  fill(rank, NN);
  topk_count_kernel<<<dim3((NN + 255) / 256, (NN + 511) / 512), 256, 0, stream>>>(svec, NN, rank);
  topk_place_kernel<<<(NN + 255) / 256, 256, 0, stream>>>(svec, rank, NN, KK1, perm1, vals);
  subgraph_bits_kernel<<<KK1, 256, 0, stream>>>(A0b, W0, perm1, KK1, W1, A1b);
  augment_or_kernel<<<KK1, 128, 0, stream>>>(A1b, A1ab, nullptr, dis1, W1, KK1);

  // ---- level 2 ----
  gemm_k64_kernel<<<(KK1 + 3) / 4, 256, 0, stream>>>(x1, w2, perm1, vals, dis1, xw, KK1);
  spmm_nbr_kernel<<<(KK1 + 3) / 4, 256, 0, stream>>>(A1ab, W1, xw, nullptr, dis1, b2,
      p2wrel, p2wroot, tvec, rvec, nullptr, nullptr, x2, KK1, 0);
  matvec_bits_kernel<<<(KK1 + 3) / 4, 256, 0, stream>>>(A1ab, W1, tvec, rvec, p2brel, nullptr, svec, KK1);
  fill(rank, NN);
  topk_count_kernel<<<dim3((KK1 + 255) / 256, (KK1 + 511) / 512), 256, 0, stream>>>(svec, KK1, rank);
  topk_place_kernel<<<(KK1 + 255) / 256, 256, 0, stream>>>(svec, rank, KK1, KK2, perm2, vals);
  subgraph_bits_kernel<<<KK2, 256, 0, stream>>>(A1ab, W1, perm2, KK2, W2, A2b);
  // A2a is ~99.98% dense: emit only the complement (holes) + dis2
  augment_or_kernel<<<KK2, 128, 0, stream>>>(A2b, nullptr, H2b, dis2, W2, KK2);

  // ---- level 3 (complement trick: A2a@B = colsum(B) - holes@B) ----
  gemm_k64_kernel<<<(KK2 + 3) / 4, 256, 0, stream>>>(x2, w3, perm2, vals, dis2, xw, KK2);
  colsum_part_kernel<<<(KK2 + 63) / 64, 256, 0, stream>>>(xw, KK2, part);
  colsum_final_kernel<<<1, 256, 0, stream>>>(part, (KK2 + 63) / 64, csum);
  spmm_nbr_kernel<<<(KK2 + 3) / 4, 256, 0, stream>>>(H2b, W2, xw, csum, dis2, b3,
      p3wrel, p3wroot, tvec, rvec, nullptr, nullptr, x3, KK2, 0);
  vec_total_kernel<<<1, 256, 0, stream>>>(tvec, KK2, tot);
  matvec_bits_kernel<<<(KK2 + 3) / 4, 256, 0, stream>>>(H2b, W2, tvec, rvec, p3brel, tot, svec, KK2);
  fill(rank, NN);
  topk_count_kernel<<<dim3((KK2 + 255) / 256, (KK2 + 511) / 512), 256, 0, stream>>>(svec, KK2, rank);
  topk_place_kernel<<<(KK2 + 255) / 256, 256, 0, stream>>>(svec, rank, KK2, KK3, perm3, vals);
  scatter_gate_kernel<<<(KK3 + 3) / 4, 256, 0, stream>>>(x3, perm3, vals, dis2, up0, KK3);

  // ---- decoder ----
  gemm_k64_kernel<<<(KK2 + 3) / 4, 256, 0, stream>>>(up0, u0w, nullptr, nullptr, nullptr, xw, KK2);
  colsum_part_kernel<<<(KK2 + 63) / 64, 256, 0, stream>>>(xw, KK2, part);
  colsum_final_kernel<<<1, 256, 0, stream>>>(part, (KK2 + 63) / 64, csum);
  spmm_nbr_kernel<<<(KK2 + 3) / 4, 256, 0, stream>>>(H2b, W2, xw, csum, dis2, u0b,
      nullptr, nullptr, nullptr, nullptr, perm2, dis1, up1, KK2, 1);

  gemm_k64_kernel<<<(KK1 + 3) / 4, 256, 0, stream>>>(up1, u1w, nullptr, nullptr, nullptr, xw, KK1);
  spmm_nbr_kernel<<<(KK1 + 3) / 4, 256, 0, stream>>>(A1ab, W1, xw, nullptr, dis1, u1b,
      nullptr, nullptr, nullptr, nullptr, perm1, dis0, up2, KK1, 1);

  // final GCN reassociated: out = (dis0 .* (A0 @ up2)) @ u2w + u2b
  spmm_nbr_kernel<<<NN / 4, 256, 0, stream>>>(A0b, W0, up2, nullptr, dis0, nullptr,
      nullptr, nullptr, nullptr, nullptr, nullptr, nullptr, y0, NN, 0);
  gemm_wide4_kernel<<<NN / 4, 256, 0, stream>>>(y0, u2w, u2b, out, NN);
}